// Round 1
// baseline (294.441 us; speedup 1.0000x reference)
//
#include <hip/hip_runtime.h>

typedef unsigned short u16;
typedef unsigned int   u32;
typedef __attribute__((ext_vector_type(8))) short short8;
typedef __attribute__((ext_vector_type(4))) float f32x4;

#define T_TOK 8192
#define DIM   1024
#define NEXP  8
#define NPAIR (T_TOK * 2)   // 16384 token-expert pairs

__device__ __forceinline__ u16 f2bf(float f) {
  u32 u = __builtin_bit_cast(u32, f);
  u32 r = (u + 0x7fffu + ((u >> 16) & 1u)) >> 16;  // RNE
  return (u16)r;
}
__device__ __forceinline__ float bf2f(u16 b) {
  return __builtin_bit_cast(float, ((u32)b) << 16);
}

__device__ __forceinline__ void gl_lds16(const u16* g, u16* l) {
  __builtin_amdgcn_global_load_lds(
      (const __attribute__((address_space(1))) u32*)g,
      (__attribute__((address_space(3))) u32*)l,
      16, 0, 0);
}

// ---------------- fp32 -> bf16 cast, 8 elems/thread ----------------
__global__ void cast_bf16_k(const float* __restrict__ src, u16* __restrict__ dst, int n) {
  int i = (blockIdx.x * 256 + threadIdx.x) * 8;
  if (i >= n) return;
  f32x4 a = *(const f32x4*)(src + i);
  f32x4 b = *(const f32x4*)(src + i + 4);
  short8 o;
  o[0] = (short)f2bf(a[0]); o[1] = (short)f2bf(a[1]);
  o[2] = (short)f2bf(a[2]); o[3] = (short)f2bf(a[3]);
  o[4] = (short)f2bf(b[0]); o[5] = (short)f2bf(b[1]);
  o[6] = (short)f2bf(b[2]); o[7] = (short)f2bf(b[3]);
  *(short8*)(dst + i) = o;
}

// ---------------- bucket pairs by expert (single block) ----------------
__global__ void sort_pairs_k(const int* __restrict__ idx,
                             int* __restrict__ counts, int* __restrict__ offsets,
                             int* __restrict__ bucket, int* __restrict__ pos) {
  __shared__ int lc[NEXP], lo[NEXP], lcur[NEXP];
  const int tid = threadIdx.x;  // 1024 threads
  if (tid < NEXP) lc[tid] = 0;
  __syncthreads();
  for (int i = tid; i < NPAIR; i += 1024) atomicAdd(&lc[idx[i]], 1);
  __syncthreads();
  if (tid == 0) {
    int s = 0;
    for (int e = 0; e < NEXP; ++e) { lo[e] = s; lcur[e] = s; s += lc[e]; }
  }
  __syncthreads();
  for (int i = tid; i < NPAIR; i += 1024) {
    int e = idx[i];
    int p = atomicAdd(&lcur[e], 1);
    bucket[p] = i;
    pos[i] = p;
  }
  if (tid < NEXP) { counts[tid] = lc[tid]; offsets[tid] = lo[tid]; }
}

// ---------------- grouped GEMM: O[p] = relu(Arow[p] @ W[e]^T), bf16 ----------------
// 128x128x32 tiles, global_load_lds staging, 16x16x32 bf16 MFMA, 4 waves (2x2), 4x4 frags each.
template <int GATHER>
__global__ __launch_bounds__(256, 2)
void moe_gemm_k(const u16* __restrict__ A,      // bf16 rows: x_bf16 [T][D] (GATHER) or h [NPAIR][D]
                const u16* __restrict__ W,      // bf16 [E][D][D], torch layout [out][in]
                u16* __restrict__ O,            // bf16 [NPAIR][D]
                const int* __restrict__ counts,
                const int* __restrict__ offsets,
                const int* __restrict__ bucket) {
  const int e   = blockIdx.z;
  const int cnt = counts[e];
  const int m0  = blockIdx.y << 7;
  if (m0 >= cnt) return;
  const int seg = offsets[e];
  const int n0  = blockIdx.x << 7;

  __shared__ u16 As[128 * 32];  // 8 KB, row-major [m][k]
  __shared__ u16 Bs[128 * 32];  // 8 KB, row-major [n][k]

  const int tid  = threadIdx.x;
  const int lane = tid & 63;
  const int wave = tid >> 6;

  // Staging: tile = 512 chunks of 16B; wave issues 2 A + 2 B global_load_lds per k-step.
  int aoff[2], boff[2];
#pragma unroll
  for (int j = 0; j < 2; ++j) {
    const int c  = ((wave << 1) + j) * 64 + lane;  // chunk 0..511
    const int r  = c >> 2;                         // tile row
    const int kc = (c & 3) << 3;                   // elem offset in row
    int p = seg + m0 + r;
    p = (p < seg + cnt) ? p : (seg + cnt - 1);     // clamp tail rows
    int rowbase;
    if (GATHER) { const int pair = bucket[p]; rowbase = (pair >> 1) * DIM; }
    else        { rowbase = p * DIM; }
    aoff[j] = rowbase + kc;
    boff[j] = e * DIM * DIM + (n0 + r) * DIM + kc;
  }

  f32x4 acc[4][4] = {};

  const int wm   = (wave >> 1) << 6;
  const int wn   = (wave & 1) << 6;
  const int lr   = lane & 15;
  const int quad = lane >> 4;

  for (int k0 = 0; k0 < DIM; k0 += 32) {
    __syncthreads();  // protect LDS reuse
#pragma unroll
    for (int j = 0; j < 2; ++j) {
      const int instr = (wave << 1) + j;
      gl_lds16(A + aoff[j] + k0, &As[instr << 9]);
      gl_lds16(W + boff[j] + k0, &Bs[instr << 9]);
    }
    __syncthreads();  // drains vmcnt for global_load_lds

    short8 af[4], bf[4];
#pragma unroll
    for (int mi = 0; mi < 4; ++mi)
      af[mi] = *(const short8*)&As[(wm + (mi << 4) + lr) * 32 + (quad << 3)];
#pragma unroll
    for (int ni = 0; ni < 4; ++ni)
      bf[ni] = *(const short8*)&Bs[(wn + (ni << 4) + lr) * 32 + (quad << 3)];
#pragma unroll
    for (int mi = 0; mi < 4; ++mi)
#pragma unroll
      for (int ni = 0; ni < 4; ++ni)
        acc[mi][ni] = __builtin_amdgcn_mfma_f32_16x16x32_bf16(af[mi], bf[ni], acc[mi][ni], 0, 0, 0);
  }

  // Epilogue: relu -> bf16. C/D layout: col = lane&15, row = quad*4 + reg.
  const int pend = seg + cnt;
#pragma unroll
  for (int mi = 0; mi < 4; ++mi) {
#pragma unroll
    for (int ni = 0; ni < 4; ++ni) {
      const int col = n0 + wn + (ni << 4) + lr;
#pragma unroll
      for (int r4 = 0; r4 < 4; ++r4) {
        const int p = seg + m0 + wm + (mi << 4) + (quad << 2) + r4;
        if (p < pend) {
          float v = acc[mi][ni][r4];
          v = v > 0.f ? v : 0.f;
          O[(size_t)p * DIM + col] = f2bf(v);
        }
      }
    }
  }
}

// ---------------- combine: out[t] = w0*y[pos[2t]] + w1*y[pos[2t+1]] ----------------
__global__ void combine_k(const u16* __restrict__ y, const int* __restrict__ pos,
                          const float* __restrict__ wts, float* __restrict__ out) {
  const int t    = blockIdx.x * 2 + (threadIdx.x >> 7);
  const int lane = threadIdx.x & 127;
  const int col  = lane * 8;
  const int p0 = pos[2 * t], p1 = pos[2 * t + 1];
  const float w0 = wts[2 * t], w1 = wts[2 * t + 1];
  const short8 a = *(const short8*)(y + (size_t)p0 * DIM + col);
  const short8 b = *(const short8*)(y + (size_t)p1 * DIM + col);
  f32x4 o0, o1;
#pragma unroll
  for (int j = 0; j < 8; ++j) {
    float v = w0 * bf2f((u16)a[j]) + w1 * bf2f((u16)b[j]);
    if (j < 4) o0[j] = v; else o1[j - 4] = v;
  }
  float* op = out + (size_t)t * DIM + col;
  *(f32x4*)op = o0;
  *(f32x4*)(op + 4) = o1;
}

extern "C" void kernel_launch(void* const* d_in, const int* in_sizes, int n_in,
                              void* d_out, int out_size, void* d_ws, size_t ws_size,
                              hipStream_t stream) {
  const float* x   = (const float*)d_in[0];
  const int*   idx = (const int*)d_in[1];
  const float* wts = (const float*)d_in[2];
  const float* W1  = (const float*)d_in[3];
  const float* W2  = (const float*)d_in[4];
  float* out = (float*)d_out;

  // Workspace layout (y aliases the dead x_bf16+W1_bf16 regions after layer 1)
  char* ws = (char*)d_ws;
  int* counts  = (int*)ws;               // 8
  int* offsets = (int*)(ws + 32);        // 8
  int* bucket  = (int*)(ws + 256);       // 16384
  int* pos     = (int*)(ws + 256 + 4 * NPAIR);
  const size_t base = 131328;            // 16B-aligned
  const size_t MB16 = 16ull * 1024 * 1024;
  u16* xb  = (u16*)(ws + base);                 // 16 MB
  u16* w1b = (u16*)(ws + base + MB16);          // 16 MB
  u16* w2b = (u16*)(ws + base + 2 * MB16);      // 16 MB
  u16* h   = (u16*)(ws + base + 3 * MB16);      // 32 MB
  u16* yb  = xb;                                // 32 MB, aliases xb+w1b (both dead)

  const int nX = T_TOK * DIM;        // 8388608
  const int nW = NEXP * DIM * DIM;   // 8388608

  cast_bf16_k<<<nX / 2048, 256, 0, stream>>>(x, xb, nX);
  cast_bf16_k<<<nW / 2048, 256, 0, stream>>>(W1, w1b, nW);
  cast_bf16_k<<<nW / 2048, 256, 0, stream>>>(W2, w2b, nW);

  sort_pairs_k<<<1, 1024, 0, stream>>>(idx, counts, offsets, bucket, pos);

  dim3 gg(DIM / 128, NPAIR / 128, NEXP);  // (8, 128, 8); tail blocks early-exit
  moe_gemm_k<1><<<gg, 256, 0, stream>>>(xb, w1b, h, counts, offsets, bucket);
  moe_gemm_k<0><<<gg, 256, 0, stream>>>(h, w2b, yb, counts, offsets, bucket);

  combine_k<<<T_TOK / 2, 256, 0, stream>>>(yb, pos, wts, out);
}